// Round 3
// baseline (344.278 us; speedup 1.0000x reference)
//
#include <hip/hip_runtime.h>

#define TT 48
#define DD 32
#define HH 64
#define BB 16384
#define BM 32

typedef __bf16 bf16x8 __attribute__((ext_vector_type(8)));
typedef float f32x4 __attribute__((ext_vector_type(4)));
typedef unsigned short us4 __attribute__((ext_vector_type(4)));

// LDS: [32 rows][128B] tiles: h hi/lo double-buffered, xw hi/lo double-buffered = 32 KB
#define HOFF(b, p) (((b) * 2 + (p)) * 4096)
#define XWOFF(b, p) (16384 + ((b) * 2 + (p)) * 4096)
#define MFMA(a, b, c) __builtin_amdgcn_mfma_f32_16x16x32_bf16(a, b, c, 0, 0, 0)

static __device__ __forceinline__ int swz(int row, int kb) {
  return row * 128 + (kb ^ ((row & 7) << 4));
}
static __device__ __forceinline__ unsigned short bfu(float f) {
  __bf16 b = (__bf16)f;
  return __builtin_bit_cast(unsigned short, b);
}
static __device__ __forceinline__ float bff(unsigned short u) {
  return (float)__builtin_bit_cast(__bf16, u);
}
static __device__ __forceinline__ float sigm(float v) {
  return __builtin_amdgcn_rcpf(1.f + __expf(-v));
}
static __device__ __forceinline__ float tanh_f(float v) {
  // 1 - 2/(1+e^{2x}); saturates correctly at +-inf
  return fmaf(-2.f, __builtin_amdgcn_rcpf(1.f + __expf(2.f * v)), 1.f);
}

// ------------------------------------------------------------------
// Kernel 0: split W into bf16 hi/lo, reorder gate rows n' = hg*64 + g*16 + h4
// (orig row = g*64 + hg*16 + h4) so i/f/g/o of one (row,hidx) share a lane.
// ------------------------------------------------------------------
__global__ void prep_kernel(const float* __restrict__ W_ih, const float* __restrict__ W_hh,
                            const float* __restrict__ b_ih, const float* __restrict__ b_hh,
                            unsigned short* __restrict__ Whh_hi, unsigned short* __restrict__ Whh_lo,
                            unsigned short* __restrict__ Wih_hi, unsigned short* __restrict__ Wih_lo,
                            float* __restrict__ bsum) {
  int np = threadIdx.x;  // 256 threads, 1 block
  int hg = np >> 6, g = (np >> 4) & 3, h4 = np & 15;
  int orig = g * 64 + hg * 16 + h4;
  bsum[np] = b_ih[orig] + b_hh[orig];
  for (int k = 0; k < 64; ++k) {
    float w = W_hh[orig * 64 + k];
    unsigned short hi = bfu(w);
    Whh_hi[np * 64 + k] = hi;
    Whh_lo[np * 64 + k] = bfu(w - bff(hi));
  }
  for (int k = 0; k < 32; ++k) {
    float w = W_ih[orig * 32 + k];
    unsigned short hi = bfu(w);
    Wih_hi[np * 32 + k] = hi;
    Wih_lo[np * 32 + k] = bfu(w - bff(hi));
  }
}

// ------------------------------------------------------------------
// Kernel 1: attention. a[b,:] = softmax_d( sum_t x[b,t,d]*w_att[2H+t] )
// (h/c/b_att terms are uniform over d -> softmax-invariant -> dropped).
// ------------------------------------------------------------------
__global__ __launch_bounds__(256) void attn_kernel(const float* __restrict__ x,
                                                   const float* __restrict__ W_att,
                                                   float* __restrict__ out0) {
  int tid = threadIdx.x;
  int b = blockIdx.x * 32 + (tid >> 3);
  int dq = (tid & 7) * 4;
  const float* xb = x + (size_t)b * (TT * DD);
  float px = 0.f, py = 0.f, pz = 0.f, pw = 0.f;
#pragma unroll 4
  for (int t = 0; t < TT; ++t) {
    float w = W_att[2 * HH + t];
    float4 xv = *(const float4*)(xb + t * DD + dq);
    px = fmaf(xv.x, w, px);
    py = fmaf(xv.y, w, py);
    pz = fmaf(xv.z, w, pz);
    pw = fmaf(xv.w, w, pw);
  }
  float m = fmaxf(fmaxf(px, py), fmaxf(pz, pw));
#pragma unroll
  for (int s = 1; s < 8; s <<= 1) m = fmaxf(m, __shfl_xor(m, s));
  float ex = __expf(px - m), ey = __expf(py - m), ez = __expf(pz - m), ew = __expf(pw - m);
  float sum = ex + ey + ez + ew;
#pragma unroll
  for (int s = 1; s < 8; s <<= 1) sum += __shfl_xor(sum, s);
  float inv = __builtin_amdgcn_rcpf(sum);
  float4 a;
  a.x = ex * inv; a.y = ey * inv; a.z = ez * inv; a.w = ew * inv;
  float* o = out0 + (size_t)b * (TT * DD) + dq;
#pragma unroll 4
  for (int t = 0; t < TT; ++t) *(float4*)(o + t * DD) = a;
}

// ------------------------------------------------------------------
// Kernel 2: persistent LSTM recurrence. 512 blocks x 512 thr (8 waves),
// 32 rows/block — same global footprint as the 54-MB-FETCH round-1 config,
// 2x the waves. Wave w: row-half mt=w>>2, hidx slice wid4=w&3 (16 hidx, all
// 4 gates). W frags resident in registers (bf16 hi/lo); h & xw exchanged via
// double-buffered swizzled LDS, 1 barrier/step.
// Split precision: Ahi*Bhi + Alo*Bhi + Ahi*Blo.
// ------------------------------------------------------------------
__global__ __launch_bounds__(512, 4) void lstm_kernel(
    const float* __restrict__ x, const float* __restrict__ h0, const float* __restrict__ c0,
    const float* __restrict__ a_src,
    const unsigned short* __restrict__ Whh_hi, const unsigned short* __restrict__ Whh_lo,
    const unsigned short* __restrict__ Wih_hi, const unsigned short* __restrict__ Wih_lo,
    const float* __restrict__ bsum, float* __restrict__ out1) {
  __shared__ __align__(16) char smem[32768];
  const int tid = threadIdx.x;
  const int w = tid >> 6;
  const int mt = w >> 2;    // row-half: rows [mt*16, mt*16+16)
  const int wid4 = w & 3;   // hidx slice: [wid4*16, wid4*16+16)
  const int l = tid & 63;
  const int h4 = l & 15;
  const int lg = l >> 4;
  const int br0 = blockIdx.x * BM;

  // resident W fragments: whh[g][kchunk][hi/lo], wih[g][hi/lo]
  bf16x8 whh[4][2][2];
  bf16x8 wih[4][2];
#pragma unroll
  for (int g = 0; g < 4; ++g) {
    int np = wid4 * 64 + g * 16 + h4;
#pragma unroll
    for (int c = 0; c < 2; ++c) {
      whh[g][c][0] = *(const bf16x8*)(Whh_hi + np * 64 + c * 32 + lg * 8);
      whh[g][c][1] = *(const bf16x8*)(Whh_lo + np * 64 + c * 32 + lg * 8);
    }
    wih[g][0] = *(const bf16x8*)(Wih_hi + np * 32 + lg * 8);
    wih[g][1] = *(const bf16x8*)(Wih_lo + np * 32 + lg * 8);
  }
  float b4[4];
#pragma unroll
  for (int g = 0; g < 4; ++g) b4[g] = bsum[wid4 * 64 + g * 16 + h4];

  // c state in C-tile layout: row = mt*16 + lg*4 + r, col hidx = wid4*16 + h4
  f32x4 creg;
#pragma unroll
  for (int r = 0; r < 4; ++r)
    creg[r] = c0[(size_t)(br0 + mt * 16 + lg * 4 + r) * HH + wid4 * 16 + h4];

  // staging thread mapping: row = tid>>4 (0..31), j-pair = (tid&15)*2
  const int srow = tid >> 4;
  const int sj = (tid & 15) * 2;
  const float* xrow = x + (size_t)(br0 + srow) * (TT * DD) + sj;
  float2 a2 = *(const float2*)(a_src + (size_t)(br0 + srow) * (TT * DD) + sj);

  // prologue: h0 -> hbuf[0] (4 h values/thread), xw(t=0) -> xwbuf[0]
  {
    const int hx = (tid & 15) * 4;
    float4 v = *(const float4*)(h0 + (size_t)(br0 + srow) * HH + hx);
    us4 hi, lo;
    unsigned short h;
    h = bfu(v.x); hi.x = h; lo.x = bfu(v.x - bff(h));
    h = bfu(v.y); hi.y = h; lo.y = bfu(v.y - bff(h));
    h = bfu(v.z); hi.z = h; lo.z = bfu(v.z - bff(h));
    h = bfu(v.w); hi.w = h; lo.w = bfu(v.w - bff(h));
    *(us4*)(smem + HOFF(0, 0) + swz(srow, hx * 2)) = hi;
    *(us4*)(smem + HOFF(0, 1) + swz(srow, hx * 2)) = lo;
    float2 xv = *(const float2*)(xrow);
    float w0 = xv.x * a2.x, w1 = xv.y * a2.y;
    unsigned short h0b = bfu(w0), h1b = bfu(w1);
    unsigned int hp = (unsigned int)h0b | ((unsigned int)h1b << 16);
    unsigned int lp = (unsigned int)bfu(w0 - bff(h0b)) | ((unsigned int)bfu(w1 - bff(h1b)) << 16);
    *(unsigned int*)(smem + XWOFF(0, 0) + swz(srow, sj * 2)) = hp;
    *(unsigned int*)(smem + XWOFF(0, 1) + swz(srow, sj * 2)) = lp;
  }
  __syncthreads();

#pragma unroll 2
  for (int t = 0; t < TT; ++t) {
    const int cur = t & 1, nxt = cur ^ 1;
    // (1) issue next x tile load early
    float2 xv;
    const bool stage = (t + 1 < TT);
    if (stage) xv = *(const float2*)(xrow + (t + 1) * DD);

    // (2) A-fragment reads from current buffers (rows of this wave's M-tile)
    bf16x8 ah[2][2], axw[2];
    const int arow = mt * 16 + h4;
#pragma unroll
    for (int c = 0; c < 2; ++c) {
      ah[c][0] = *(const bf16x8*)(smem + HOFF(cur, 0) + swz(arow, c * 64 + lg * 16));
      ah[c][1] = *(const bf16x8*)(smem + HOFF(cur, 1) + swz(arow, c * 64 + lg * 16));
    }
    axw[0] = *(const bf16x8*)(smem + XWOFF(cur, 0) + swz(arow, lg * 16));
    axw[1] = *(const bf16x8*)(smem + XWOFF(cur, 1) + swz(arow, lg * 16));

    // (3) MFMA
    f32x4 gacc[4];
#pragma unroll
    for (int g = 0; g < 4; ++g) {
      f32x4 acc = {b4[g], b4[g], b4[g], b4[g]};
      acc = MFMA(ah[0][0], whh[g][0][0], acc);
      acc = MFMA(ah[0][1], whh[g][0][0], acc);
      acc = MFMA(ah[0][0], whh[g][0][1], acc);
      acc = MFMA(ah[1][0], whh[g][1][0], acc);
      acc = MFMA(ah[1][1], whh[g][1][0], acc);
      acc = MFMA(ah[1][0], whh[g][1][1], acc);
      acc = MFMA(axw[0], wih[g][0], acc);
      acc = MFMA(axw[1], wih[g][0], acc);
      acc = MFMA(axw[0], wih[g][1], acc);
      gacc[g] = acc;
    }

    // (4) pointwise + h round-trip
#pragma unroll
    for (int r = 0; r < 4; ++r) {
      float ig = sigm(gacc[0][r]);
      float fg = sigm(gacc[1][r]);
      float gg = tanh_f(gacc[2][r]);
      float og = sigm(gacc[3][r]);
      float cn = fg * creg[r] + ig * gg;
      creg[r] = cn;
      float hn = og * tanh_f(cn);
      const int row = mt * 16 + lg * 4 + r;
      out1[((size_t)(br0 + row) * TT + t) * HH + wid4 * 16 + h4] = hn;
      unsigned short hb = bfu(hn);
      const int kb = (wid4 * 16 + h4) * 2;
      *(unsigned short*)(smem + HOFF(nxt, 0) + swz(row, kb)) = hb;
      *(unsigned short*)(smem + HOFF(nxt, 1) + swz(row, kb)) = bfu(hn - bff(hb));
    }

    // (5) finish xw staging for t+1
    if (stage) {
      float w0 = xv.x * a2.x, w1 = xv.y * a2.y;
      unsigned short h0b = bfu(w0), h1b = bfu(w1);
      unsigned int hp = (unsigned int)h0b | ((unsigned int)h1b << 16);
      unsigned int lp = (unsigned int)bfu(w0 - bff(h0b)) | ((unsigned int)bfu(w1 - bff(h1b)) << 16);
      *(unsigned int*)(smem + XWOFF(nxt, 0) + swz(srow, sj * 2)) = hp;
      *(unsigned int*)(smem + XWOFF(nxt, 1) + swz(srow, sj * 2)) = lp;
    }
    __syncthreads();
  }
}

extern "C" void kernel_launch(void* const* d_in, const int* in_sizes, int n_in,
                              void* d_out, int out_size, void* d_ws, size_t ws_size,
                              hipStream_t stream) {
  const float* x = (const float*)d_in[0];
  const float* h0 = (const float*)d_in[1];
  const float* c0 = (const float*)d_in[2];
  const float* W_att = (const float*)d_in[3];
  // d_in[4] = b_att: uniform shift, softmax-invariant -> unused
  const float* W_ih = (const float*)d_in[5];
  const float* W_hh = (const float*)d_in[6];
  const float* b_ih = (const float*)d_in[7];
  const float* b_hh = (const float*)d_in[8];

  float* out0 = (float*)d_out;                // attention [B,T,D]
  float* out1 = out0 + (size_t)BB * TT * DD;  // input_encoded [B,T,H]

  char* ws = (char*)d_ws;
  unsigned short* Whh_hi = (unsigned short*)ws;            // 32768 B
  unsigned short* Whh_lo = (unsigned short*)(ws + 32768);  // 32768 B
  unsigned short* Wih_hi = (unsigned short*)(ws + 65536);  // 16384 B
  unsigned short* Wih_lo = (unsigned short*)(ws + 81920);  // 16384 B
  float* bsum = (float*)(ws + 98304);                      // 1024 B

  prep_kernel<<<1, 256, 0, stream>>>(W_ih, W_hh, b_ih, b_hh,
                                     Whh_hi, Whh_lo, Wih_hi, Wih_lo, bsum);
  attn_kernel<<<BB / 32, 256, 0, stream>>>(x, W_att, out0);
  // kernel 2 reads a[b,d] from the t=0 slice of out0 (== a broadcast)
  lstm_kernel<<<BB / BM, 512, 0, stream>>>(x, h0, c0, out0,
                                           Whh_hi, Whh_lo, Wih_hi, Wih_lo, bsum, out1);
}

// Round 4
// 192.044 us; speedup vs baseline: 1.7927x; 1.7927x over previous
//
#include <hip/hip_runtime.h>

#define TT 48
#define DD 32
#define HH 64
#define BB 16384
#define BM 32

typedef __bf16 bf16x8 __attribute__((ext_vector_type(8)));
typedef float f32x4 __attribute__((ext_vector_type(4)));
typedef unsigned short us4 __attribute__((ext_vector_type(4)));
typedef unsigned short us8 __attribute__((ext_vector_type(8)));

// LDS: [32 rows][128B] tiles: h hi/lo double-buffered, xw hi/lo double-buffered = 32 KB
#define HOFF(b, p) (((b) * 2 + (p)) * 4096)
#define XWOFF(b, p) (16384 + ((b) * 2 + (p)) * 4096)
#define MFMA(a, b, c) __builtin_amdgcn_mfma_f32_16x16x32_bf16(a, b, c, 0, 0, 0)

static __device__ __forceinline__ int swz(int row, int kb) {
  return row * 128 + (kb ^ ((row & 7) << 4));
}
static __device__ __forceinline__ unsigned short bfu(float f) {
  __bf16 b = (__bf16)f;
  return __builtin_bit_cast(unsigned short, b);
}
static __device__ __forceinline__ float bff(unsigned short u) {
  return (float)__builtin_bit_cast(__bf16, u);
}
static __device__ __forceinline__ float sigm(float v) {
  return __builtin_amdgcn_rcpf(1.f + __expf(-v));
}
static __device__ __forceinline__ float tanh_f(float v) {
  // 1 - 2/(1+e^{2x}); saturates correctly at +-inf
  return fmaf(-2.f, __builtin_amdgcn_rcpf(1.f + __expf(2.f * v)), 1.f);
}
static __device__ __forceinline__ void store_hilo(char* smem, int offHi, int offLo,
                                                  int row, int kb, float4 v) {
  us4 hi, lo;
  unsigned short h;
  h = bfu(v.x); hi.x = h; lo.x = bfu(v.x - bff(h));
  h = bfu(v.y); hi.y = h; lo.y = bfu(v.y - bff(h));
  h = bfu(v.z); hi.z = h; lo.z = bfu(v.z - bff(h));
  h = bfu(v.w); hi.w = h; lo.w = bfu(v.w - bff(h));
  *(us4*)(smem + offHi + swz(row, kb)) = hi;
  *(us4*)(smem + offLo + swz(row, kb)) = lo;
}

// ------------------------------------------------------------------
// Kernel 0: split W into bf16 hi/lo, reorder gate rows n' = hg*64 + g*16 + h4
// (orig row = g*64 + hg*16 + h4) so i/f/g/o of one (row,hidx) share a lane.
// ------------------------------------------------------------------
__global__ void prep_kernel(const float* __restrict__ W_ih, const float* __restrict__ W_hh,
                            const float* __restrict__ b_ih, const float* __restrict__ b_hh,
                            unsigned short* __restrict__ Whh_hi, unsigned short* __restrict__ Whh_lo,
                            unsigned short* __restrict__ Wih_hi, unsigned short* __restrict__ Wih_lo,
                            float* __restrict__ bsum) {
  int np = threadIdx.x;  // 256 threads, 1 block
  int hg = np >> 6, g = (np >> 4) & 3, h4 = np & 15;
  int orig = g * 64 + hg * 16 + h4;
  bsum[np] = b_ih[orig] + b_hh[orig];
  for (int k = 0; k < 64; ++k) {
    float w = W_hh[orig * 64 + k];
    unsigned short hi = bfu(w);
    Whh_hi[np * 64 + k] = hi;
    Whh_lo[np * 64 + k] = bfu(w - bff(hi));
  }
  for (int k = 0; k < 32; ++k) {
    float w = W_ih[orig * 32 + k];
    unsigned short hi = bfu(w);
    Wih_hi[np * 32 + k] = hi;
    Wih_lo[np * 32 + k] = bfu(w - bff(hi));
  }
}

// ------------------------------------------------------------------
// Kernel 1: attention. a[b,:] = softmax_d( sum_t x[b,t,d]*w_att[2H+t] )
// (h/c/b_att terms are uniform over d -> softmax-invariant -> dropped).
// ------------------------------------------------------------------
__global__ __launch_bounds__(256) void attn_kernel(const float* __restrict__ x,
                                                   const float* __restrict__ W_att,
                                                   float* __restrict__ out0) {
  int tid = threadIdx.x;
  int b = blockIdx.x * 32 + (tid >> 3);
  int dq = (tid & 7) * 4;
  const float* xb = x + (size_t)b * (TT * DD);
  float px = 0.f, py = 0.f, pz = 0.f, pw = 0.f;
#pragma unroll 4
  for (int t = 0; t < TT; ++t) {
    float w = W_att[2 * HH + t];
    float4 xv = *(const float4*)(xb + t * DD + dq);
    px = fmaf(xv.x, w, px);
    py = fmaf(xv.y, w, py);
    pz = fmaf(xv.z, w, pz);
    pw = fmaf(xv.w, w, pw);
  }
  float m = fmaxf(fmaxf(px, py), fmaxf(pz, pw));
#pragma unroll
  for (int s = 1; s < 8; s <<= 1) m = fmaxf(m, __shfl_xor(m, s));
  float ex = __expf(px - m), ey = __expf(py - m), ez = __expf(pz - m), ew = __expf(pw - m);
  float sum = ex + ey + ez + ew;
#pragma unroll
  for (int s = 1; s < 8; s <<= 1) sum += __shfl_xor(sum, s);
  float inv = __builtin_amdgcn_rcpf(sum);
  float4 a;
  a.x = ex * inv; a.y = ey * inv; a.z = ez * inv; a.w = ew * inv;
  float* o = out0 + (size_t)b * (TT * DD) + dq;
#pragma unroll 4
  for (int t = 0; t < TT; ++t) *(float4*)(o + t * DD) = a;
}

// ------------------------------------------------------------------
// Kernel 2: persistent LSTM recurrence. 512 blocks x 256 thr, 32 rows/block
// (round-1 structure: the only config with sane FETCH). Wave w owns hidx
// [16w,16w+16) for all 32 rows, all 4 gates. W frags in registers (bf16
// hi/lo); h & xw via double-buffered swizzled LDS, 1 barrier/step.
// out1 is written FULL-LINE: h goes to LDS (needed for recurrence anyway),
// and the next iteration's staging threads emit float4 stores covering
// contiguous 128B lines — no partial-line RMW fills.
// ------------------------------------------------------------------
__global__ __launch_bounds__(256) void lstm_kernel(
    const float* __restrict__ x, const float* __restrict__ h0, const float* __restrict__ c0,
    const float* __restrict__ a_src,
    const unsigned short* __restrict__ Whh_hi, const unsigned short* __restrict__ Whh_lo,
    const unsigned short* __restrict__ Wih_hi, const unsigned short* __restrict__ Wih_lo,
    const float* __restrict__ bsum, float* __restrict__ out1) {
  __shared__ __align__(16) char smem[32768];
  const int tid = threadIdx.x;
  const int wid = tid >> 6;
  const int l = tid & 63;
  const int h4 = l & 15;
  const int lg = l >> 4;
  const int br0 = blockIdx.x * BM;

  // resident W fragments: whh[g][kchunk][hi/lo], wih[g][hi/lo]
  bf16x8 whh[4][2][2];
  bf16x8 wih[4][2];
#pragma unroll
  for (int g = 0; g < 4; ++g) {
    int np = wid * 64 + g * 16 + h4;
#pragma unroll
    for (int c = 0; c < 2; ++c) {
      whh[g][c][0] = *(const bf16x8*)(Whh_hi + np * 64 + c * 32 + lg * 8);
      whh[g][c][1] = *(const bf16x8*)(Whh_lo + np * 64 + c * 32 + lg * 8);
    }
    wih[g][0] = *(const bf16x8*)(Wih_hi + np * 32 + lg * 8);
    wih[g][1] = *(const bf16x8*)(Wih_lo + np * 32 + lg * 8);
  }
  float b4[4];
#pragma unroll
  for (int g = 0; g < 4; ++g) b4[g] = bsum[wid * 64 + g * 16 + h4];

  // c state in C-tile layout: row = mt*16 + lg*4 + r, col hidx = wid*16 + h4
  f32x4 creg[2];
#pragma unroll
  for (int mt = 0; mt < 2; ++mt)
#pragma unroll
    for (int r = 0; r < 4; ++r)
      creg[mt][r] = c0[(size_t)(br0 + mt * 16 + lg * 4 + r) * HH + wid * 16 + h4];

  // staging thread mapping: row = tid>>3 (0..31), j-quad = (tid&7)*4, h-oct = (tid&7)*8
  const int srow = tid >> 3;
  const int sj = (tid & 7) * 4;
  const int hx = (tid & 7) * 8;
  const int hx2 = hx * 2;  // byte offset of h-oct in LDS row
  const float* xrow = x + (size_t)(br0 + srow) * (TT * DD);
  float4 a4 = *(const float4*)(a_src + (size_t)(br0 + srow) * (TT * DD) + sj);
  float* o1row = out1 + (size_t)(br0 + srow) * (TT * HH) + hx;

  // prologue: h0 -> hbuf[0], xw(t=0) -> xwbuf[0]
  {
    float4 v0 = *(const float4*)(h0 + (size_t)(br0 + srow) * HH + hx);
    float4 v1 = *(const float4*)(h0 + (size_t)(br0 + srow) * HH + hx + 4);
    store_hilo(smem, HOFF(0, 0), HOFF(0, 1), srow, hx2, v0);
    store_hilo(smem, HOFF(0, 0), HOFF(0, 1), srow, hx2 + 8, v1);
    float4 xv = *(const float4*)(xrow + sj);
    float4 wv;
    wv.x = xv.x * a4.x; wv.y = xv.y * a4.y; wv.z = xv.z * a4.z; wv.w = xv.w * a4.w;
    store_hilo(smem, XWOFF(0, 0), XWOFF(0, 1), srow, sj * 2, wv);
  }
  __syncthreads();

  for (int t = 0; t < TT; ++t) {
    const int cur = t & 1, nxt = cur ^ 1;
    // (1) issue next x tile load early
    float4 xv;
    const bool stage = (t + 1 < TT);
    if (stage) xv = *(const float4*)(xrow + (t + 1) * DD + sj);

    // (1b) writeback h_{t-1} -> out1 as full-line float4 stores (reads buf cur,
    // which is only read by everyone this iteration; no extra barrier needed)
    if (t > 0) {
      us8 hi = *(const us8*)(smem + HOFF(cur, 0) + swz(srow, hx2));
      us8 lo = *(const us8*)(smem + HOFF(cur, 1) + swz(srow, hx2));
      float4 o0, o1;
      o0.x = bff(hi[0]) + bff(lo[0]); o0.y = bff(hi[1]) + bff(lo[1]);
      o0.z = bff(hi[2]) + bff(lo[2]); o0.w = bff(hi[3]) + bff(lo[3]);
      o1.x = bff(hi[4]) + bff(lo[4]); o1.y = bff(hi[5]) + bff(lo[5]);
      o1.z = bff(hi[6]) + bff(lo[6]); o1.w = bff(hi[7]) + bff(lo[7]);
      float* orow = o1row + (size_t)(t - 1) * HH;
      *(float4*)(orow) = o0;
      *(float4*)(orow + 4) = o1;
    }

    // (2) A-fragment reads from current buffers
    bf16x8 ah[2][2][2], axw[2][2];
#pragma unroll
    for (int mt = 0; mt < 2; ++mt) {
      const int arow = mt * 16 + h4;
#pragma unroll
      for (int c = 0; c < 2; ++c) {
        ah[mt][c][0] = *(const bf16x8*)(smem + HOFF(cur, 0) + swz(arow, c * 64 + lg * 16));
        ah[mt][c][1] = *(const bf16x8*)(smem + HOFF(cur, 1) + swz(arow, c * 64 + lg * 16));
      }
      axw[mt][0] = *(const bf16x8*)(smem + XWOFF(cur, 0) + swz(arow, lg * 16));
      axw[mt][1] = *(const bf16x8*)(smem + XWOFF(cur, 1) + swz(arow, lg * 16));
    }

    // (3) MFMA + pointwise per M-tile
#pragma unroll
    for (int mt = 0; mt < 2; ++mt) {
      f32x4 gacc[4];
#pragma unroll
      for (int g = 0; g < 4; ++g) {
        f32x4 acc = {b4[g], b4[g], b4[g], b4[g]};
        acc = MFMA(ah[mt][0][0], whh[g][0][0], acc);
        acc = MFMA(ah[mt][0][1], whh[g][0][0], acc);
        acc = MFMA(ah[mt][0][0], whh[g][0][1], acc);
        acc = MFMA(ah[mt][1][0], whh[g][1][0], acc);
        acc = MFMA(ah[mt][1][1], whh[g][1][0], acc);
        acc = MFMA(ah[mt][1][0], whh[g][1][1], acc);
        acc = MFMA(axw[mt][0], wih[g][0], acc);
        acc = MFMA(axw[mt][1], wih[g][0], acc);
        acc = MFMA(axw[mt][0], wih[g][1], acc);
        gacc[g] = acc;
      }
#pragma unroll
      for (int r = 0; r < 4; ++r) {
        float ig = sigm(gacc[0][r]);
        float fg = sigm(gacc[1][r]);
        float gg = tanh_f(gacc[2][r]);
        float og = sigm(gacc[3][r]);
        float cn = fg * creg[mt][r] + ig * gg;
        creg[mt][r] = cn;
        float hn = og * tanh_f(cn);
        const int row = mt * 16 + lg * 4 + r;
        unsigned short hb = bfu(hn);
        const int kb = (wid * 16 + h4) * 2;
        *(unsigned short*)(smem + HOFF(nxt, 0) + swz(row, kb)) = hb;
        *(unsigned short*)(smem + HOFF(nxt, 1) + swz(row, kb)) = bfu(hn - bff(hb));
      }
    }
    // (4) finish xw staging for t+1
    if (stage) {
      float4 wv;
      wv.x = xv.x * a4.x; wv.y = xv.y * a4.y; wv.z = xv.z * a4.z; wv.w = xv.w * a4.w;
      store_hilo(smem, XWOFF(nxt, 0), XWOFF(nxt, 1), srow, sj * 2, wv);
    }
    __syncthreads();
  }

  // epilogue: writeback h_{TT-1} (sits in buf[TT&1] = buf0)
  {
    us8 hi = *(const us8*)(smem + HOFF(TT & 1, 0) + swz(srow, hx2));
    us8 lo = *(const us8*)(smem + HOFF(TT & 1, 1) + swz(srow, hx2));
    float4 o0, o1;
    o0.x = bff(hi[0]) + bff(lo[0]); o0.y = bff(hi[1]) + bff(lo[1]);
    o0.z = bff(hi[2]) + bff(lo[2]); o0.w = bff(hi[3]) + bff(lo[3]);
    o1.x = bff(hi[4]) + bff(lo[4]); o1.y = bff(hi[5]) + bff(lo[5]);
    o1.z = bff(hi[6]) + bff(lo[6]); o1.w = bff(hi[7]) + bff(lo[7]);
    float* orow = o1row + (size_t)(TT - 1) * HH;
    *(float4*)(orow) = o0;
    *(float4*)(orow + 4) = o1;
  }
}

extern "C" void kernel_launch(void* const* d_in, const int* in_sizes, int n_in,
                              void* d_out, int out_size, void* d_ws, size_t ws_size,
                              hipStream_t stream) {
  const float* x = (const float*)d_in[0];
  const float* h0 = (const float*)d_in[1];
  const float* c0 = (const float*)d_in[2];
  const float* W_att = (const float*)d_in[3];
  // d_in[4] = b_att: uniform shift, softmax-invariant -> unused
  const float* W_ih = (const float*)d_in[5];
  const float* W_hh = (const float*)d_in[6];
  const float* b_ih = (const float*)d_in[7];
  const float* b_hh = (const float*)d_in[8];

  float* out0 = (float*)d_out;                // attention [B,T,D]
  float* out1 = out0 + (size_t)BB * TT * DD;  // input_encoded [B,T,H]

  char* ws = (char*)d_ws;
  unsigned short* Whh_hi = (unsigned short*)ws;            // 32768 B
  unsigned short* Whh_lo = (unsigned short*)(ws + 32768);  // 32768 B
  unsigned short* Wih_hi = (unsigned short*)(ws + 65536);  // 16384 B
  unsigned short* Wih_lo = (unsigned short*)(ws + 81920);  // 16384 B
  float* bsum = (float*)(ws + 98304);                      // 1024 B

  prep_kernel<<<1, 256, 0, stream>>>(W_ih, W_hh, b_ih, b_hh,
                                     Whh_hi, Whh_lo, Wih_hi, Wih_lo, bsum);
  attn_kernel<<<BB / 32, 256, 0, stream>>>(x, W_att, out0);
  // kernel 2 reads a[b,d] from the t=0 slice of out0 (== a broadcast)
  lstm_kernel<<<BB / BM, 256, 0, stream>>>(x, h0, c0, out0,
                                           Whh_hi, Whh_lo, Wih_hi, Wih_lo, bsum, out1);
}